// Round 6
// baseline (72.969 us; speedup 1.0000x reference)
//
#include <hip/hip_runtime.h>
#include <math.h>

#define N_BOXES 10647
#define NUM_CLASSES 80
#define MAX_BOXES 20
#define IOU_T 0.1f
#define SCORE_T 0.3f

// Fixed window threshold. scores ~ U[0,1): E[wcnt] = 10647*0.008 = 85,
// sd 9.2. P(wcnt > 128) ~ 1e-6/class. Violations -> exact Phase E.
#define WND_T 0.992f

#define NT 1024
#define NWAVES (NT / 64)
#define WCAP 128   // window capacity (LDS)

// k1: 167 transpose/slot tiles. k2: 80 NMS blocks + 6 copy blocks.
#define TROWS 64
#define TBLOCKS 167     // ceil(10647 / 64)
#define CPBLOCKS 6
#define K2_BLOCKS (NUM_CLASSES + CPBLOCKS)

// Workspace slots: per (class, tile) 8 key slots + 8 box slots. Every KEY
// slot is written by k1 (zeros for empty) -> poison-safe. Box slots are
// written iff the key slot is valid and read iff valid. >8 candidates in
// one tile (P ~ 5e-5/run) -> SENTINEL -> exact Phase E.
#define WSLOTS 8
#define SLOT_N (TBLOCKS * WSLOTS)          // 1336 per class
#define KEYS_N (NUM_CLASSES * SLOT_N)      // 106880 u64 = 855 KB
#define SENTINEL (~0ull)
#define BOX_OFF KEYS_N                     // float4 boxes, same indexing

// Output layout (all float32, concatenated):
//   [0)      boxes copy        N_BOXES*4               = 42588
//   [42588)  scores transposed NUM_CLASSES*N_BOXES     = 851760
//   [894348) nms_final         NUM_CLASSES*MAX_BOXES*3 = 4800
#define OUT_OFF_SCORES (N_BOXES * 4)
#define OUT_OFF_NMS (N_BOXES * 4 + NUM_CLASSES * N_BOXES)

// R19: single-variable change vs R18 — k1's transposed-column store phase
// emitted 5120 scalar VMEM stores/block (5/thread, 4B/lane); at 1-4cy
// issue each that is 2-8us of k1 critical path, the largest computable
// body chunk left. Replace with aligned float4 body stores (+ scalar
// head/tail: column base c*10647 is odd-aligned for 3/4 of classes) ->
// ~1700 store instrs/block. k2 byte-identical to R18. If delta <= 1us,
// bodies are minor and the rest is harness floor.
#define FOR_K(OP) OP(0) OP(1) OP(2) OP(3) OP(4) OP(5) OP(6) OP(7) OP(8) OP(9) OP(10)

// Reference-exact IoU>T test (individually rounded float32 ops; inter==0 =>
// reference IoU is 0 => not suppressed, divide skipped). First box is the
// SELECTED box (reference's area1 = selected's area, added first).
__device__ __forceinline__ bool iou_gt(float jy1, float jx1, float jy2,
                                       float jx2, float area_j, float4 b) {
    float ty = fmaxf(jy1, b.x);
    float tx = fmaxf(jx1, b.y);
    float by = fminf(jy2, b.z);
    float bx = fminf(jx2, b.w);
    float dy = fmaxf(__fsub_rn(by, ty), 0.0f);
    float dx = fmaxf(__fsub_rn(bx, tx), 0.0f);
    float inter = __fmul_rn(dy, dx);
    if (!(inter > 0.0f)) return false;
    float area_i = __fmul_rn(__fsub_rn(b.z, b.x), __fsub_rn(b.w, b.y));
    float uni = __fsub_rn(__fadd_rn(area_j, area_i), inter);
    float iou = (uni > 0.0f) ? __fdiv_rn(inter, uni) : 0.0f;
    return iou > IOU_T;
}

// ---------------------------------------------------------------------------
// Kernel 1: coalesced transpose of scores [N,C]->[C,N] into out (float4
// column stores), plus per-(class,tile) candidate key+box slot writes.
// ---------------------------------------------------------------------------
__global__ __launch_bounds__(NT) void transpose_slots_kernel(
    const float* __restrict__ boxes, const float* __restrict__ scores,
    float* __restrict__ out, unsigned long long* __restrict__ ws) {
    const int tid = threadIdx.x;
    const int b = blockIdx.x;

    __shared__ float lds[TROWS * 81];  // [r][c], pad 81 -> conflict-free
    __shared__ float4 s_tb[TROWS];     // this tile's boxes
    const int r0 = b * TROWS;
    const int nr = min(TROWS, N_BOXES - r0);

    // Tile boxes: one coalesced wave-load (64 x 16B contiguous).
    if (tid < TROWS) {
        s_tb[tid] = (r0 + tid < N_BOXES)
                        ? ((const float4*)boxes)[r0 + tid]
                        : make_float4(0.f, 0.f, 0.f, 0.f);
    }

    // Read: contiguous chunk scores[r0*80 .. (r0+nr)*80), float4 loads.
    const int nq = nr * 20;  // 80 floats/row = 20 float4/row
    for (int q = tid; q < nq; q += NT) {
        const int r = q / 20;
        const int c4 = (q - r * 20) * 4;
        float4 v = *(const float4*)(scores + (r0 + r) * NUM_CLASSES + c4);
        float* dst = &lds[r * 81 + c4];
        dst[0] = v.x;
        dst[1] = v.y;
        dst[2] = v.z;
        dst[3] = v.w;
    }
    __syncthreads();

    // ---- Store phase: 16 threads per class; float4 body + scalar
    // head/tail (column base OUT_OFF_SCORES + c*10647 + r0 is 16B-aligned
    // only when (c*3 + r0) % 4 == 0, so peel h = (-base)&3 scalar rows).
    // Pass 1: classes 0..63 (all 16 waves); pass 2: classes 64..79.
    // LDS read banks: word addr (rr+j)*81 + c, stride 324 % 32 = 4 ->
    // 2-way within a class group (free), distinct across groups.
    #pragma unroll
    for (int pass = 0; pass < 2; ++pass) {
        const int ci = pass * 64 + (tid >> 4);
        const int rq = tid & 15;
        if (ci < NUM_CLASSES) {
            float* colo = out + OUT_OFF_SCORES + ci * N_BOXES + r0;
            const unsigned B0 = (unsigned)(OUT_OFF_SCORES + ci * N_BOXES + r0);
            int h = (4 - (B0 & 3)) & 3;  // scalar head rows
            if (h > nr) h = nr;
            const int kb = (nr - h) >> 2;  // # aligned float4 chunks (<=16)
            if (rq < kb) {
                const int rr = h + 4 * rq;
                float4 v;
                v.x = lds[(rr + 0) * 81 + ci];
                v.y = lds[(rr + 1) * 81 + ci];
                v.z = lds[(rr + 2) * 81 + ci];
                v.w = lds[(rr + 3) * 81 + ci];
                *(float4*)(colo + rr) = v;
            } else if (rq == 15) {
                // head (<=3 rows) + tail (<=3 rows) scalars
                for (int j = 0; j < h; ++j) colo[j] = lds[j * 81 + ci];
                for (int j = h + 4 * kb; j < nr; ++j)
                    colo[j] = lds[j * 81 + ci];
            }
        }
    }

    // ---- Slot pass: wave chi owns classes {p*16+chi}; lane = row.
    // Candidate ballot -> rank-compacted key+box slot writes.
    unsigned long long* wskeys = ws;
    float4* wsboxes = (float4*)(ws + BOX_OFF);
    const int r = tid & (TROWS - 1);
    const int chi = tid >> 6;
    #pragma unroll
    for (int p = 0; p < 5; ++p) {
        const int c = p * 16 + chi;
        const float v = (r < nr) ? lds[r * 81 + c] : 0.0f;
        const bool cand = (r < nr) && (v >= WND_T);
        const unsigned long long mask = __ballot(cand);
        const int cnt = __popcll(mask);
        const int base = (c * TBLOCKS + b) * WSLOTS;
        if (cnt <= WSLOTS) {
            if (cand) {
                const int rank = __popcll(mask & ((1ull << r) - 1ull));
                wskeys[base + rank] =
                    ((unsigned long long)__float_as_uint(v) << 32) |
                    (0xFFFFFFFFu - (unsigned)(r0 + r));
                wsboxes[base + rank] = s_tb[r];
            }
            if (r >= cnt && r < WSLOTS) wskeys[base + r] = 0ull;
        } else {
            // pathological tie burst -> sentinel -> k2 overflow -> Phase E
            if (r == 0) wskeys[base] = SENTINEL;
            if (r >= 1 && r < WSLOTS) wskeys[base + r] = 0ull;
        }
    }
}

// ---------------------------------------------------------------------------
// Kernel 2: per-class NMS from pre-compacted slots (blocks 0..79) + boxes
// copy (blocks 80..85). Byte-identical to R18.
// ---------------------------------------------------------------------------
__global__ __launch_bounds__(NT) void nms_kernel(
    const float* __restrict__ boxes, float* __restrict__ out,
    const unsigned long long* __restrict__ ws) {
    const int tid = threadIdx.x;
    const int c = blockIdx.x;

    if (c >= NUM_CLASSES) {
        // ---- boxes copy: coalesced both sides ----
        for (int q = (c - NUM_CLASSES) * NT + tid; q < N_BOXES;
             q += CPBLOCKS * NT) {
            ((float4*)out)[q] = ((const float4*)boxes)[q];
        }
        return;
    }

    const int wave = tid >> 6;
    const int lane = tid & 63;
    const float4* boxes4 = (const float4*)boxes;
    const float* col = out + OUT_OFF_SCORES + c * N_BOXES;  // Phase E only

    __shared__ unsigned long long s_k[WCAP];        // window keys (unsorted)
    __shared__ float4 s_b4[WCAP];                   // window boxes (unsorted)
    __shared__ unsigned long long s_ks[WCAP];       // sorted keys
    __shared__ float4 s_bs[WCAP];                   // sorted boxes
    __shared__ __align__(16) unsigned long long s_mask[WCAP][2];
    __shared__ unsigned long long s_rk[2][NWAVES];  // fallback reduce
    __shared__ int s_out[MAX_BOXES];
    __shared__ int s_cnt, s_nsel, s_ovf;

    if (tid < MAX_BOXES) s_out[tid] = -1;
    if (tid == 0) { s_cnt = 0; s_nsel = 0; s_ovf = 0; }
    __syncthreads();

    // ---- Phase C': slot scan (keys 10.7 KB, L2-warm from k1) ----
    const unsigned long long* wsk = ws + (size_t)c * SLOT_N;
    const float4* wsb = ((const float4*)(ws + BOX_OFF)) + (size_t)c * SLOT_N;
    for (int q = tid; q < SLOT_N; q += NT) {
        unsigned long long s = wsk[q];
        bool val = false;
        if (s != 0ull) {
            if ((unsigned)(s >> 32) >= 0x3F800000u) {
                s_ovf = 1;  // sentinel (benign same-value LDS race)
            } else {
                val = true;
            }
        }
        const unsigned long long m = __ballot(val);
        int basew = 0;
        if (lane == 0 && m) basew = atomicAdd(&s_cnt, __popcll(m));
        basew = __shfl(basew, 0);
        if (val) {
            const int pos = basew + __popcll(m & ((1ull << lane) - 1ull));
            if (pos < WCAP) {
                s_k[pos] = s;
                s_b4[pos] = wsb[q];  // box rode along in the slot (L2-warm)
            }
        }
    }
    __syncthreads();

    const int wcnt = s_cnt;
    const bool overflow = (wcnt > WCAP) || (s_ovf != 0);

    // ---- Phase D1: parallel rank sort (threads 0..wcnt) ----
    if (!overflow && tid < wcnt) {
        const unsigned long long mykey = s_k[tid];
        const float4 mybox = s_b4[tid];
        int rank = 0;
        for (int j = 0; j < wcnt; ++j) rank += (s_k[j] > mykey) ? 1 : 0;
        s_ks[rank] = mykey;
        s_bs[rank] = mybox;
    }
    __syncthreads();

    // ---- Phase D2: parallel suppression bit-matrix (ballot per task) ----
    if (!overflow) {
        const int ntask = 2 * wcnt;
        for (int t = wave; t < ntask; t += NWAVES) {
            const int row = t >> 1, ch = t & 1;
            float4 rb = s_bs[row];
            float area_r =
                __fmul_rn(__fsub_rn(rb.z, rb.x), __fsub_rn(rb.w, rb.y));
            int colj = ch * 64 + lane;
            bool s = (colj < wcnt) &&
                     iou_gt(rb.x, rb.y, rb.z, rb.w, area_r, s_bs[colj]);
            unsigned long long m = __ballot(s);
            if (lane == 0) s_mask[row][ch] = m;
        }
    }
    __syncthreads();

    // ---- Phase D3: serial resolve, masks/keys in wave-0 registers ----
    if (wave == 0 && !overflow) {
        const unsigned long long pA0 = s_mask[lane][0];
        const unsigned long long pA1 = s_mask[lane][1];
        const unsigned long long pB0 = s_mask[64 + lane][0];
        const unsigned long long pB1 = s_mask[64 + lane][1];
        const unsigned long long kA = s_ks[lane];
        const unsigned long long kB = s_ks[64 + lane];
        unsigned long long a0, a1;
        if (wcnt >= 64) {
            a0 = ~0ull;
            a1 = (wcnt >= 128) ? ~0ull
                               : ((wcnt > 64) ? ((1ull << (wcnt - 64)) - 1)
                                              : 0ull);
        } else {
            a0 = (wcnt > 0) ? ((1ull << wcnt) - 1) : 0ull;
            a1 = 0ull;
        }
        int nkept = 0;
        while ((a0 | a1) != 0 && nkept < MAX_BOXES) {
            int pos;
            unsigned long long mx, my, kk;
            if (a0) {  // wave-uniform branch
                pos = __builtin_ctzll(a0);
                mx = __shfl(pA0, pos);
                my = __shfl(pA1, pos);
                kk = __shfl(kA, pos);
            } else {
                const int p1 = __builtin_ctzll(a1);
                mx = __shfl(pB0, p1);
                my = __shfl(pB1, p1);
                kk = __shfl(kB, p1);
                pos = 64 + p1;
            }
            if (lane == 0)
                s_out[nkept] = (int)(0xFFFFFFFFu - (unsigned int)kk);
            ++nkept;
            a0 &= ~mx;
            a1 &= ~my;
            if (pos < 64) a0 &= ~(1ull << pos);
            else a1 &= ~(1ull << (pos - 64));
        }
        if (lane == 0) s_nsel = nkept;
    }
    __syncthreads();

    // ---- Phase E: exact fallback (window exhausted early / overflow).
    // Never triggers on typical data; correctness path only.
    const int nsel0 = s_nsel;
    const bool needs_more = (nsel0 < MAX_BOXES);
    if (needs_more) {
#define DECL_K(k) unsigned long long k_##k = 0;
        FOR_K(DECL_K)
#undef DECL_K
#define BUILDE_K(k)                                                      \
        {                                                                \
            int i = tid + (k)*NT;                                        \
            if (i < N_BOXES) {                                           \
                float v = col[i];                                        \
                if (v >= SCORE_T) {                                      \
                    bool dead = (!overflow && v >= WND_T);               \
                    if (!dead && nsel0 > 0) {                            \
                        float4 bi = boxes4[i];                           \
                        for (int j = 0; j < nsel0; ++j) {                \
                            float4 sb = boxes4[s_out[j]];                \
                            float aj =                                   \
                                __fmul_rn(__fsub_rn(sb.z, sb.x),         \
                                          __fsub_rn(sb.w, sb.y));        \
                            if (iou_gt(sb.x, sb.y, sb.z, sb.w, aj,       \
                                       bi)) {                            \
                                dead = true;                             \
                                break;                                   \
                            }                                            \
                        }                                                \
                    }                                                    \
                    if (!dead)                                           \
                        k_##k = ((unsigned long long)__float_as_uint(v)  \
                                 << 32) |                                \
                                (0xFFFFFFFFu - (unsigned int)i);         \
                }                                                        \
            }                                                            \
        }
        FOR_K(BUILDE_K)
#undef BUILDE_K
        #pragma unroll 1
        for (int slot = nsel0; slot < MAX_BOXES; ++slot) {
            unsigned long long bk = 0;
#define MAXK_K(k) if (k_##k > bk) bk = k_##k;
            FOR_K(MAXK_K)
#undef MAXK_K
            #pragma unroll
            for (int off = 32; off >= 1; off >>= 1) {
                unsigned long long o =
                    (unsigned long long)__shfl_xor((long long)bk, off);
                if (o > bk) bk = o;
            }
            const int par = slot & 1;
            if (lane == 0) s_rk[par][wave] = bk;
            __syncthreads();
            unsigned long long f = s_rk[par][0];
            #pragma unroll
            for (int w = 1; w < NWAVES; ++w) {
                unsigned long long o = s_rk[par][w];
                if (o > f) f = o;
            }
            if (f == 0) break;  // uniform
            const int widx = (int)(0xFFFFFFFFu - (unsigned int)f);
            if (tid == 0) s_out[slot] = widx;
            float4 wb = boxes4[widx];  // uniform L1 broadcast
            const float area_j =
                __fmul_rn(__fsub_rn(wb.z, wb.x), __fsub_rn(wb.w, wb.y));
#define SCANE_K(k)                                                      \
            if (k_##k != 0) {                                           \
                int i = tid + (k)*NT;                                   \
                float4 bb = boxes4[i];                                  \
                if (i == widx ||                                        \
                    iou_gt(wb.x, wb.y, wb.z, wb.w, area_j, bb))         \
                    k_##k = 0;                                          \
            }
            FOR_K(SCANE_K)
#undef SCANE_K
        }
    }

    // ---- emit rows ----
    __syncthreads();
    if (tid < MAX_BOXES) {
        int bi = s_out[tid];
        int o = OUT_OFF_NMS + c * MAX_BOXES * 3 + tid * 3;
        if (bi >= 0) {
            out[o + 0] = 0.0f;
            out[o + 1] = (float)c;
            out[o + 2] = (float)bi;
        } else {
            out[o + 0] = -1.0f;
            out[o + 1] = -1.0f;
            out[o + 2] = -1.0f;
        }
    }
}

extern "C" void kernel_launch(void* const* d_in, const int* in_sizes, int n_in,
                              void* d_out, int out_size, void* d_ws,
                              size_t ws_size, hipStream_t stream) {
    const float* boxes = (const float*)d_in[0];   // [N,4] fp32
    const float* scores = (const float*)d_in[1];  // [N,C] fp32
    float* out = (float*)d_out;
    unsigned long long* ws = (unsigned long long*)d_ws;  // ~2.6 MB used

    // Launch 1: transpose (float4 column stores) + key/box slot production.
    transpose_slots_kernel<<<TBLOCKS, NT, 0, stream>>>(boxes, scores, out, ws);
    // Launch 2: NMS from slots (80 blocks) + boxes copy (6 blocks).
    nms_kernel<<<K2_BLOCKS, NT, 0, stream>>>(boxes, out, ws);
}